// Round 7
// baseline (899.787 us; speedup 1.0000x reference)
//
#include <hip/hip_runtime.h>
#include <math.h>

#define NB 16
#define NPTS 2048
#define DIN 1280
#define DM 256
#define BNROWS (NB * NPTS)   // 32768

typedef __attribute__((ext_vector_type(8))) short bf16x8;   // 8 bf16 = 4 VGPRs
typedef __attribute__((ext_vector_type(4))) float f32x4;

#define SHIFT2 23.083120654223414f   // 16 * log2(e)

// RNE float -> bf16 bits (inputs finite)
static __device__ __forceinline__ ushort f2bf(float f) {
    uint x = __float_as_uint(f);
    return (ushort)((x + 0x7FFF + ((x >> 16) & 1)) >> 16);
}

// pack 2 floats -> 2 bf16 in one u32 (gfx950 HW instruction, RNE)
static __device__ __forceinline__ uint cvtpk(float lo, float hi) {
    uint r;
    asm("v_cvt_pk_bf16_f32 %0, %1, %2" : "=v"(r) : "v"(lo), "v"(hi));
    return r;
}

// ---------------------------------------------------------------------------
// convert_wt: Wt[n][k] = bf16(W[k][n]).  Coalesced reads, scattered writes
// (writes are fire-and-forget; reads would stall).
// ---------------------------------------------------------------------------
__global__ __launch_bounds__(256)
void convert_wt(const float* __restrict__ W, ushort* __restrict__ Wt,
                const int K, const int N)
{
    const int idx = blockIdx.x * 256 + threadIdx.x;   // idx = k*N + n
    if (idx >= K * N) return;
    const int k = idx / N, n = idx - k * N;
    Wt[(size_t)n * K + k] = f2bf(W[idx]);
}

// ---------------------------------------------------------------------------
// proj_mfma: out_bf16 = bf16(A(Mx1280)@W + bias + pos_embed), plus confidence
// logits[row] += sum_c (A@W+bias)[row][c] * Wc[c]  (atomic; pre-pos values).
// Software-pipelined: A(k+32) + B(k+32) issued after the barrier, latency
// hidden under the 16 MFMAs of step k.  A-tile LDS is XOR-swizzled
// (byte ^= ((row>>1)&3)<<4, write AND read) -> <=2-way bank conflict (free).
// grid (BNROWS/64), block 256.
// ---------------------------------------------------------------------------
__global__ __launch_bounds__(256)
void proj_mfma(const float* __restrict__ A, const ushort* __restrict__ Wt,
               const float* __restrict__ bias, const float* __restrict__ Wc,
               const float* __restrict__ xyz, ushort* __restrict__ out,
               float* __restrict__ logits)
{
    __shared__ ushort Al[64 * 32];   // 4 KB, swizzled [m][k] bf16 tile
    __shared__ float invfreq[42];
    const int t = threadIdx.x;
    const int lane = t & 63, w = t >> 6;
    const int col15 = lane & 15, sub = lane >> 4;
    const int m0 = blockIdx.x * 64;

    if (t < 42) invfreq[t] = __expf((float)(2 * t) * (-9.210340371976184f / 84.0f));

    f32x4 acc[4][4];
    #pragma unroll
    for (int s = 0; s < 4; ++s)
        #pragma unroll
        for (int u = 0; u < 4; ++u) acc[s][u] = (f32x4){0.f, 0.f, 0.f, 0.f};

    const float* Ag = A + (size_t)(m0 + (t >> 2)) * DIN + (t & 3) * 8;
    const ushort* Wg[4];
    #pragma unroll
    for (int u = 0; u < 4; ++u)
        Wg[u] = Wt + (size_t)(w * 64 + u * 16 + col15) * DIN + sub * 8;

    // swizzled LDS addresses (write: row = t>>2; read: row = s*16+col15)
    char* const lds_w = (char*)Al + ((t * 16) ^ ((((t >> 2) >> 1) & 3) << 4));
    const int rd_sw = (((col15 >> 1) & 3) << 4);

    // prologue: preload k0 = 0
    float4 a0 = *(const float4*)(Ag);
    float4 a1 = *(const float4*)(Ag + 4);
    bf16x8 bcur[4];
    #pragma unroll
    for (int u = 0; u < 4; ++u) bcur[u] = *(const bf16x8*)(Wg[u]);

    #pragma unroll 2
    for (int k0 = 0; k0 < DIN; k0 += 32) {
        uint p[4];
        p[0] = cvtpk(a0.x, a0.y); p[1] = cvtpk(a0.z, a0.w);
        p[2] = cvtpk(a1.x, a1.y); p[3] = cvtpk(a1.z, a1.w);
        __syncthreads();                 // prior iter's LDS reads done
        *(uint4*)lds_w = *(uint4*)p;
        __syncthreads();                 // tile visible
        // prefetch next step (latency hides under MFMAs below)
        const int kn = (k0 + 32 < DIN) ? (k0 + 32) : 0;
        a0 = *(const float4*)(Ag + kn);
        a1 = *(const float4*)(Ag + kn + 4);
        bf16x8 bnext[4];
        #pragma unroll
        for (int u = 0; u < 4; ++u) bnext[u] = *(const bf16x8*)(Wg[u] + kn);
        #pragma unroll
        for (int s = 0; s < 4; ++s) {
            const bf16x8 af = *(const bf16x8*)((const char*)Al +
                (((s * 16 + col15) * 64 + sub * 16) ^ rd_sw));
            #pragma unroll
            for (int u = 0; u < 4; ++u)
                acc[s][u] = __builtin_amdgcn_mfma_f32_16x16x32_bf16(af, bcur[u], acc[s][u], 0, 0, 0);
        }
        #pragma unroll
        for (int u = 0; u < 4; ++u) bcur[u] = bnext[u];
    }

    // epilogue: bias, confidence logits, pos-embed, bf16 store
    float bias_u[4], wc_u[4];
    int   cidx[4];
    #pragma unroll
    for (int u = 0; u < 4; ++u) {
        cidx[u]  = w * 64 + u * 16 + col15;
        bias_u[u] = bias[cidx[u]];
        wc_u[u]   = Wc[cidx[u]];
    }
    #pragma unroll
    for (int s = 0; s < 4; ++s) {
        #pragma unroll
        for (int r = 0; r < 4; ++r) {
            const int row = m0 + s * 16 + sub * 4 + r;
            const float px = xyz[(size_t)row * 3 + 0];
            const float py = xyz[(size_t)row * 3 + 1];
            const float pz = xyz[(size_t)row * 3 + 2];
            float wp = 0.f;
            #pragma unroll
            for (int u = 0; u < 4; ++u) {
                const int c = cidx[u];
                const float val = acc[s][u][r] + bias_u[u];
                wp = fmaf(val, wc_u[u], wp);
                float pv = 0.f;
                if (c < 252) {
                    const int coord = c / 84;
                    const int f = c - coord * 84;
                    const float xc = (coord == 0) ? px : ((coord == 1) ? py : pz);
                    const float vv = xc * 6.283185307179586f * invfreq[f >> 1];
                    pv = (f & 1) ? __cosf(vv) : __sinf(vv);
                }
                out[(size_t)row * DM + c] = f2bf(val + pv);
            }
            wp += __shfl_xor(wp, 1); wp += __shfl_xor(wp, 2);
            wp += __shfl_xor(wp, 4); wp += __shfl_xor(wp, 8);
            if (col15 == 0) atomicAdd(&logits[row], wp);
        }
    }
}

// ---------------------------------------------------------------------------
// qk_mfma: out_bf16 = bf16((A_bf16(Mx256) @ W + bias) * alpha)
// Same pipeline + swizzle as proj_mfma; A already bf16 (1 LDS write/step).
// ---------------------------------------------------------------------------
__global__ __launch_bounds__(256)
void qk_mfma(const ushort* __restrict__ A, const ushort* __restrict__ Wt,
             const float* __restrict__ bias, const float alpha,
             ushort* __restrict__ out)
{
    __shared__ ushort Al[64 * 32];
    const int t = threadIdx.x;
    const int lane = t & 63, w = t >> 6;
    const int col15 = lane & 15, sub = lane >> 4;
    const int m0 = blockIdx.x * 64;

    f32x4 acc[4][4];
    #pragma unroll
    for (int s = 0; s < 4; ++s)
        #pragma unroll
        for (int u = 0; u < 4; ++u) acc[s][u] = (f32x4){0.f, 0.f, 0.f, 0.f};

    const ushort* Ag = A + (size_t)(m0 + (t >> 2)) * DM + (t & 3) * 8;
    const ushort* Wg[4];
    #pragma unroll
    for (int u = 0; u < 4; ++u)
        Wg[u] = Wt + (size_t)(w * 64 + u * 16 + col15) * DM + sub * 8;

    char* const lds_w = (char*)Al + ((t * 16) ^ ((((t >> 2) >> 1) & 3) << 4));
    const int rd_sw = (((col15 >> 1) & 3) << 4);

    uint4 av = *(const uint4*)(Ag);
    bf16x8 bcur[4];
    #pragma unroll
    for (int u = 0; u < 4; ++u) bcur[u] = *(const bf16x8*)(Wg[u]);

    #pragma unroll 2
    for (int k0 = 0; k0 < DM; k0 += 32) {
        __syncthreads();
        *(uint4*)lds_w = av;
        __syncthreads();
        const int kn = (k0 + 32 < DM) ? (k0 + 32) : 0;
        av = *(const uint4*)(Ag + kn);
        bf16x8 bnext[4];
        #pragma unroll
        for (int u = 0; u < 4; ++u) bnext[u] = *(const bf16x8*)(Wg[u] + kn);
        #pragma unroll
        for (int s = 0; s < 4; ++s) {
            const bf16x8 af = *(const bf16x8*)((const char*)Al +
                (((s * 16 + col15) * 64 + sub * 16) ^ rd_sw));
            #pragma unroll
            for (int u = 0; u < 4; ++u)
                acc[s][u] = __builtin_amdgcn_mfma_f32_16x16x32_bf16(af, bcur[u], acc[s][u], 0, 0, 0);
        }
        #pragma unroll
        for (int u = 0; u < 4; ++u) bcur[u] = bnext[u];
    }

    float bias_u[4];
    int cidx[4];
    #pragma unroll
    for (int u = 0; u < 4; ++u) {
        cidx[u] = w * 64 + u * 16 + col15;
        bias_u[u] = bias[cidx[u]];
    }
    #pragma unroll
    for (int s = 0; s < 4; ++s)
        #pragma unroll
        for (int r = 0; r < 4; ++r) {
            const int row = m0 + s * 16 + sub * 4 + r;
            #pragma unroll
            for (int u = 0; u < 4; ++u)
                out[(size_t)row * DM + cidx[u]] = f2bf((acc[s][u][r] + bias_u[u]) * alpha);
        }
}

// ---------------------------------------------------------------------------
// sigmoid_kernel: w[i] = sigmoid(w[i] + bc[0])
// ---------------------------------------------------------------------------
__global__ __launch_bounds__(256)
void sigmoid_kernel(float* __restrict__ w, const float* __restrict__ bc, int n)
{
    const int i = blockIdx.x * 256 + threadIdx.x;
    if (i < n) {
        const float z = w[i] + bc[0];
        w[i] = 1.0f / (1.0f + expf(-z));
    }
}

// ---------------------------------------------------------------------------
// attn body: compute one 16-key tile (kcur, vx/vy/vz) into the accumulators
// while prefetching the next tile (ktn) into knext / nv*.
// Q pre-scaled by log2(e)/16 so p = exp2(sv - 16*log2e) = exp(logit - 16).
// ---------------------------------------------------------------------------
static __device__ __forceinline__ void attn_body(
    const bf16x8 aq0[8], const bf16x8 aq1[8],
    const bf16x8 kcur[8], const float vx, const float vy, const float vz,
    bf16x8 knext[8], float& nvx, float& nvy, float& nvz,
    const ushort* __restrict__ Kb, const float* __restrict__ Vb,
    const int ktn, const int col, const int sub,
    float lsum[2][4], float ax[2][4], float ay[2][4], float az[2][4])
{
    const ushort* kr = Kb + (size_t)(ktn + col) * DM + sub * 8;
    #pragma unroll
    for (int c = 0; c < 8; ++c) knext[c] = *(const bf16x8*)(kr + c * 32);
    nvx = Vb[(size_t)(ktn + col) * 3 + 0];
    nvy = Vb[(size_t)(ktn + col) * 3 + 1];
    nvz = Vb[(size_t)(ktn + col) * 3 + 2];

    f32x4 sv0 = {0.f, 0.f, 0.f, 0.f};
    f32x4 sv1 = {0.f, 0.f, 0.f, 0.f};
    #pragma unroll
    for (int c = 0; c < 8; ++c) {
        sv0 = __builtin_amdgcn_mfma_f32_16x16x32_bf16(aq0[c], kcur[c], sv0, 0, 0, 0);
        sv1 = __builtin_amdgcn_mfma_f32_16x16x32_bf16(aq1[c], kcur[c], sv1, 0, 0, 0);
    }
    #pragma unroll
    for (int r = 0; r < 4; ++r) {
        const float p0 = exp2f(sv0[r] - SHIFT2);
        const float p1 = exp2f(sv1[r] - SHIFT2);
        lsum[0][r] += p0; ax[0][r] = fmaf(p0, vx, ax[0][r]);
        ay[0][r] = fmaf(p0, vy, ay[0][r]); az[0][r] = fmaf(p0, vz, az[0][r]);
        lsum[1][r] += p1; ax[1][r] = fmaf(p1, vx, ax[1][r]);
        ay[1][r] = fmaf(p1, vy, ay[1][r]); az[1][r] = fmaf(p1, vz, az[1][r]);
    }
}

// ---------------------------------------------------------------------------
// attn_mfma: MFMA flash attention, value = xyz, fixed-shift softmax (additive
// partials, key-split via blockIdx.z, atomic merge into acc4).
// Wave owns 32 queries (2 resident A-tiles = 64 VGPR -> compiler keeps them),
// processes 256 keys in 16-key tiles with ping-pong register prefetch.
// grid (NPTS/128, NB, 8) = 2048 blocks, block 256.
// ---------------------------------------------------------------------------
__global__ __launch_bounds__(256, 2)
void attn_mfma(const ushort* __restrict__ Q, const ushort* __restrict__ K,
               const float* __restrict__ V, float* __restrict__ acc4)
{
    const int b    = blockIdx.y;
    const int lane = threadIdx.x & 63;
    const int wv   = threadIdx.x >> 6;
    const int col  = lane & 15;
    const int sub  = lane >> 4;
    const int qbase = blockIdx.x * 128 + wv * 32;
    const int k0    = blockIdx.z * 256;

    const ushort* Qb = Q + (size_t)b * NPTS * DM;
    const ushort* Kb = K + (size_t)b * NPTS * DM;
    const float*  Vb = V + (size_t)b * NPTS * 3;

    // resident Q fragments: 2 tiles x 8 k-chunks = 64 VGPRs
    bf16x8 aq0[8], aq1[8];
    {
        const ushort* q0 = Qb + (size_t)(qbase + col) * DM + sub * 8;
        const ushort* q1 = Qb + (size_t)(qbase + 16 + col) * DM + sub * 8;
        #pragma unroll
        for (int c = 0; c < 8; ++c) {
            aq0[c] = *(const bf16x8*)(q0 + c * 32);
            aq1[c] = *(const bf16x8*)(q1 + c * 32);
        }
    }

    float lsum[2][4], ax[2][4], ay[2][4], az[2][4];
    #pragma unroll
    for (int s = 0; s < 2; ++s)
        #pragma unroll
        for (int r = 0; r < 4; ++r) {
            lsum[s][r] = 0.f; ax[s][r] = 0.f; ay[s][r] = 0.f; az[s][r] = 0.f;
        }

    // ping-pong K/V buffers
    bf16x8 kbA[8], kbB[8];
    float vxA, vyA, vzA, vxB, vyB, vzB;
    {
        const ushort* kr = Kb + (size_t)(k0 + col) * DM + sub * 8;
        #pragma unroll
        for (int c = 0; c < 8; ++c) kbA[c] = *(const bf16x8*)(kr + c * 32);
        vxA = Vb[(size_t)(k0 + col) * 3 + 0];
        vyA = Vb[(size_t)(k0 + col) * 3 + 1];
        vzA = Vb[(size_t)(k0 + col) * 3 + 2];
    }

    for (int kt = k0; kt < k0 + 256; kt += 32) {
        attn_body(aq0, aq1, kbA, vxA, vyA, vzA, kbB, vxB, vyB, vzB,
                  Kb, Vb, kt + 16, col, sub, lsum, ax, ay, az);
        int kt2 = kt + 32;
        if (kt2 >= k0 + 256) kt2 = k0;   // harmless reload on last step
        attn_body(aq0, aq1, kbB, vxB, vyB, vzB, kbA, vxA, vyA, vzA,
                  Kb, Vb, kt2, col, sub, lsum, ax, ay, az);
    }

    // merge partials across the 16 key-column lanes (fixed shift => pure sums)
    #pragma unroll
    for (int off = 1; off < 16; off <<= 1) {
        #pragma unroll
        for (int s = 0; s < 2; ++s)
            #pragma unroll
            for (int r = 0; r < 4; ++r) {
                lsum[s][r] += __shfl_xor(lsum[s][r], off);
                ax[s][r]   += __shfl_xor(ax[s][r], off);
                ay[s][r]   += __shfl_xor(ay[s][r], off);
                az[s][r]   += __shfl_xor(az[s][r], off);
            }
    }
    if (col == 0) {
        #pragma unroll
        for (int s = 0; s < 2; ++s)
            #pragma unroll
            for (int r = 0; r < 4; ++r) {
                const int row = qbase + s * 16 + sub * 4 + r;
                float* dst = acc4 + ((size_t)b * NPTS + row) * 4;
                atomicAdd(dst + 0, lsum[s][r]);
                atomicAdd(dst + 1, ax[s][r]);
                atomicAdd(dst + 2, ay[s][r]);
                atomicAdd(dst + 3, az[s][r]);
            }
    }
}

// ---------------------------------------------------------------------------
// reduce_kernel: per (batch, chunk) partial Kabsch sums (double) -> f64
// atomics into bsums.  grid (NB, 16), block 256, one row per thread.
// ---------------------------------------------------------------------------
__global__ __launch_bounds__(256)
void reduce_kernel(const float* __restrict__ xyz1, const float* __restrict__ xyz2,
                   const float* __restrict__ sacc, const float* __restrict__ tacc,
                   const float* __restrict__ srcw, const float* __restrict__ tgtw,
                   double* __restrict__ bsums)
{
    const int b = blockIdx.x;
    const int t = threadIdx.x;
    const int i = blockIdx.y * 256 + t;   // 0..4095
    double s[16];
    #pragma unroll
    for (int k = 0; k < 16; ++k) s[k] = 0.0;

    {
        float ax_, ay_, az_, bx_, by_, bz_, w;
        if (i < NPTS) {
            const size_t row = (size_t)b * NPTS + i;
            ax_ = xyz1[row * 3]; ay_ = xyz1[row * 3 + 1]; az_ = xyz1[row * 3 + 2];
            const float4 s4 = *(const float4*)(sacc + row * 4);
            const float inv = 1.0f / s4.x;
            bx_ = s4.y * inv; by_ = s4.z * inv; bz_ = s4.w * inv;
            w = srcw[row];
        } else {
            const size_t row = (size_t)b * NPTS + (i - NPTS);
            const float4 t4 = *(const float4*)(tacc + row * 4);
            const float inv = 1.0f / t4.x;
            ax_ = t4.y * inv; ay_ = t4.z * inv; az_ = t4.w * inv;
            bx_ = xyz2[row * 3]; by_ = xyz2[row * 3 + 1]; bz_ = xyz2[row * 3 + 2];
            w = tgtw[row];
        }
        const double dw = (double)w;
        const double dax = ax_, day = ay_, daz = az_;
        const double dbx = bx_, dby = by_, dbz = bz_;
        s[0] = dw;
        s[1] = dw * dax; s[2] = dw * day; s[3] = dw * daz;
        s[4] = dw * dbx; s[5] = dw * dby; s[6] = dw * dbz;
        s[7]  = dw * dax * dbx; s[8]  = dw * dax * dby; s[9]  = dw * dax * dbz;
        s[10] = dw * day * dbx; s[11] = dw * day * dby; s[12] = dw * day * dbz;
        s[13] = dw * daz * dbx; s[14] = dw * daz * dby; s[15] = dw * daz * dbz;
    }

    __shared__ double red[256][16];
    #pragma unroll
    for (int k = 0; k < 16; ++k) red[t][k] = s[k];
    __syncthreads();
    for (int step = 128; step >= 1; step >>= 1) {
        if (t < step) {
            #pragma unroll
            for (int k = 0; k < 16; ++k) red[t][k] += red[t + step][k];
        }
        __syncthreads();
    }
    if (t == 0) {
        #pragma unroll
        for (int k = 0; k < 16; ++k) atomicAdd(&bsums[b * 16 + k], red[0][k]);
    }
}

// ---------------------------------------------------------------------------
// svd_kernel: per batch weighted Kabsch via double-precision Jacobi SVD(3x3).
// 8 sweeps (quadratic convergence; >= 1e-14 by sweep ~5).
// ---------------------------------------------------------------------------
__global__ void svd_kernel(const double* __restrict__ bsums, float* __restrict__ out)
{
    const int b = threadIdx.x;
    if (b >= NB) return;
    const double* s = bsums + b * 16;
    double Wd = s[0];
    if (Wd < 1e-6) Wd = 1e-6;
    const double inv = 1.0 / Wd;

    double ca[3], cb[3];
    for (int r = 0; r < 3; ++r) { ca[r] = s[1 + r] * inv; cb[r] = s[4 + r] * inv; }
    double cov[3][3];
    for (int r = 0; r < 3; ++r)
        for (int c = 0; c < 3; ++c)
            cov[r][c] = s[7 + r * 3 + c] * inv - ca[r] * cb[c];

    double Mm[3][3];
    for (int i = 0; i < 3; ++i)
        for (int j = 0; j < 3; ++j)
            Mm[i][j] = cov[0][i] * cov[0][j] + cov[1][i] * cov[1][j] + cov[2][i] * cov[2][j];

    double Vm[3][3] = {{1, 0, 0}, {0, 1, 0}, {0, 0, 1}};
    const int PP[3] = {0, 0, 1}, QQ[3] = {1, 2, 2};
    for (int sweep = 0; sweep < 8; ++sweep) {
        for (int pi = 0; pi < 3; ++pi) {
            const int p = PP[pi], q = QQ[pi];
            const double apq = Mm[p][q];
            if (fabs(apq) < 1e-300) continue;
            const double tau = (Mm[q][q] - Mm[p][p]) / (2.0 * apq);
            const double tt = ((tau >= 0.0) ? 1.0 : -1.0) / (fabs(tau) + sqrt(1.0 + tau * tau));
            const double c = 1.0 / sqrt(1.0 + tt * tt);
            const double sn = tt * c;
            for (int k = 0; k < 3; ++k) {
                const double mkp = Mm[k][p], mkq = Mm[k][q];
                Mm[k][p] = c * mkp - sn * mkq;
                Mm[k][q] = sn * mkp + c * mkq;
            }
            for (int k = 0; k < 3; ++k) {
                const double mpk = Mm[p][k], mqk = Mm[q][k];
                Mm[p][k] = c * mpk - sn * mqk;
                Mm[q][k] = sn * mpk + c * mqk;
            }
            for (int k = 0; k < 3; ++k) {
                const double vkp = Vm[k][p], vkq = Vm[k][q];
                Vm[k][p] = c * vkp - sn * vkq;
                Vm[k][q] = sn * vkp + c * vkq;
            }
        }
    }

    double l0 = Mm[0][0], l1 = Mm[1][1], l2 = Mm[2][2];
    double v0[3], v1[3], v2[3];
    for (int k = 0; k < 3; ++k) { v0[k] = Vm[k][0]; v1[k] = Vm[k][1]; v2[k] = Vm[k][2]; }
    if (l0 < l1) { double tmp = l0; l0 = l1; l1 = tmp;
        for (int k = 0; k < 3; ++k) { double tv = v0[k]; v0[k] = v1[k]; v1[k] = tv; } }
    if (l0 < l2) { double tmp = l0; l0 = l2; l2 = tmp;
        for (int k = 0; k < 3; ++k) { double tv = v0[k]; v0[k] = v2[k]; v2[k] = tv; } }
    if (l1 < l2) { double tmp = l1; l1 = l2; l2 = tmp;
        for (int k = 0; k < 3; ++k) { double tv = v1[k]; v1[k] = v2[k]; v2[k] = tv; } }

    double u0[3], u1[3], u2[3];
    for (int r = 0; r < 3; ++r) u0[r] = cov[r][0] * v0[0] + cov[r][1] * v0[1] + cov[r][2] * v0[2];
    for (int r = 0; r < 3; ++r) u1[r] = cov[r][0] * v1[0] + cov[r][1] * v1[1] + cov[r][2] * v1[2];
    double n0 = sqrt(u0[0] * u0[0] + u0[1] * u0[1] + u0[2] * u0[2]);
    if (n0 > 1e-30) { for (int k = 0; k < 3; ++k) u0[k] /= n0; }
    else { u0[0] = 1; u0[1] = 0; u0[2] = 0; }
    const double d01 = u0[0] * u1[0] + u0[1] * u1[1] + u0[2] * u1[2];
    for (int k = 0; k < 3; ++k) u1[k] -= d01 * u0[k];
    double n1 = sqrt(u1[0] * u1[0] + u1[1] * u1[1] + u1[2] * u1[2]);
    if (n1 > 1e-30) { for (int k = 0; k < 3; ++k) u1[k] /= n1; }
    else {
        const double aa0 = fabs(u0[0]), aa1 = fabs(u0[1]), aa2 = fabs(u0[2]);
        const int ax = (aa0 <= aa1 && aa0 <= aa2) ? 0 : ((aa1 <= aa2) ? 1 : 2);
        double e[3] = {0, 0, 0}; e[ax] = 1.0;
        const double d = u0[ax];
        for (int k = 0; k < 3; ++k) u1[k] = e[k] - d * u0[k];
        const double nn = sqrt(u1[0] * u1[0] + u1[1] * u1[1] + u1[2] * u1[2]);
        for (int k = 0; k < 3; ++k) u1[k] /= nn;
    }
    u2[0] = u0[1] * u1[2] - u0[2] * u1[1];
    u2[1] = u0[2] * u1[0] - u0[0] * u1[2];
    u2[2] = u0[0] * u1[1] - u0[1] * u1[0];

    double R[3][3];
    for (int r = 0; r < 3; ++r)
        for (int c = 0; c < 3; ++c)
            R[r][c] = v0[r] * u0[c] + v1[r] * u1[c] + v2[r] * u2[c];
    const double det = R[0][0] * (R[1][1] * R[2][2] - R[1][2] * R[2][1])
                     - R[0][1] * (R[1][0] * R[2][2] - R[1][2] * R[2][0])
                     + R[0][2] * (R[1][0] * R[2][1] - R[1][1] * R[2][0]);
    if (det <= 0.0) {
        for (int r = 0; r < 3; ++r)
            for (int c = 0; c < 3; ++c)
                R[r][c] -= 2.0 * v2[r] * u2[c];
    }
    double tv[3];
    for (int r = 0; r < 3; ++r)
        tv[r] = cb[r] - (R[r][0] * ca[0] + R[r][1] * ca[1] + R[r][2] * ca[2]);

    for (int r = 0; r < 3; ++r) {
        out[b * 12 + r * 4 + 0] = (float)R[r][0];
        out[b * 12 + r * 4 + 1] = (float)R[r][1];
        out[b * 12 + r * 4 + 2] = (float)R[r][2];
        out[b * 12 + r * 4 + 3] = (float)tv[r];
    }
}

// ---------------------------------------------------------------------------
extern "C" void kernel_launch(void* const* d_in, const int* in_sizes, int n_in,
                              void* d_out, int out_size, void* d_ws, size_t ws_size,
                              hipStream_t stream)
{
    const float* feat1 = (const float*)d_in[0];
    const float* xyz1  = (const float*)d_in[1];
    const float* feat2 = (const float*)d_in[2];
    const float* xyz2  = (const float*)d_in[3];
    const float* Wf = (const float*)d_in[4];
    const float* bf = (const float*)d_in[5];
    const float* Wq = (const float*)d_in[6];
    const float* bq = (const float*)d_in[7];
    const float* Wk = (const float*)d_in[8];
    const float* bk = (const float*)d_in[9];
    const float* Wc = (const float*)d_in[10];
    const float* bc = (const float*)d_in[11];
    float* out = (float*)d_out;

    // workspace layout
    float*  srcw = (float*)d_ws;                         // BNROWS   (zeroed)
    float*  tgtw = srcw + BNROWS;                        // BNROWS   (zeroed)
    float*  sacc = tgtw + BNROWS;                        // BNROWS*4 (zeroed)
    float*  tacc = sacc + (size_t)BNROWS * 4;            // BNROWS*4 (zeroed)
    double* bsums = (double*)(tacc + (size_t)BNROWS * 4);// 256 doubles (zeroed)
    ushort* src2 = (ushort*)(bsums + NB * 16);           // BNROWS*256 bf16
    ushort* tgt2 = src2 + (size_t)BNROWS * DM;
    ushort* qbuf = tgt2 + (size_t)BNROWS * DM;
    ushort* kbuf = qbuf + (size_t)BNROWS * DM;
    ushort* wft  = kbuf + (size_t)BNROWS * DM;           // 256*1280
    ushort* wqt  = wft + 256 * 1280;                     // 256*256
    ushort* wkt  = wqt + 256 * 256;                      // 256*256

    // zero logits + attention accumulators + bsums (contiguous region)
    hipMemsetAsync(d_ws, 0, (size_t)10 * BNROWS * sizeof(float) + NB * 16 * sizeof(double), stream);

    // transpose+convert weights to bf16 [n][k]
    convert_wt<<<(DIN * DM) / 256, 256, 0, stream>>>(Wf, wft, DIN, DM);
    convert_wt<<<(DM * DM) / 256, 256, 0, stream>>>(Wq, wqt, DM, DM);
    convert_wt<<<(DM * DM) / 256, 256, 0, stream>>>(Wk, wkt, DM, DM);

    const dim3 gm(BNROWS / 64);   // 512 blocks
    proj_mfma<<<gm, 256, 0, stream>>>(feat1, wft, bf, Wc, xyz1, src2, srcw);
    proj_mfma<<<gm, 256, 0, stream>>>(feat2, wft, bf, Wc, xyz2, tgt2, tgtw);
    sigmoid_kernel<<<(2 * BNROWS) / 256, 256, 0, stream>>>(srcw, bc, 2 * BNROWS);

    // fold softmax base-2 conversion into the Q scale: alpha = log2(e)/sqrt(D)
    const float alphaQ = 1.4426950408889634f / 16.0f;
    const dim3 gattn(NPTS / 128, NB, 8);  // 2048 blocks

    // direction 1: q from src2, k from tgt2, values xyz2 -> sacc
    qk_mfma<<<gm, 256, 0, stream>>>(src2, wqt, bq, alphaQ, qbuf);
    qk_mfma<<<gm, 256, 0, stream>>>(tgt2, wkt, bk, 1.0f, kbuf);
    attn_mfma<<<gattn, 256, 0, stream>>>(qbuf, kbuf, xyz2, sacc);

    // direction 2: q from tgt2, k from src2, values xyz1 -> tacc
    qk_mfma<<<gm, 256, 0, stream>>>(tgt2, wqt, bq, alphaQ, qbuf);
    qk_mfma<<<gm, 256, 0, stream>>>(src2, wkt, bk, 1.0f, kbuf);
    attn_mfma<<<gattn, 256, 0, stream>>>(qbuf, kbuf, xyz1, tacc);

    reduce_kernel<<<dim3(NB, 16), 256, 0, stream>>>(xyz1, xyz2, sacc, tacc, srcw, tgtw, bsums);
    svd_kernel<<<1, 64, 0, stream>>>(bsums, out);
}